// Round 15
// baseline (323.520 us; speedup 1.0000x reference)
//
#include <hip/hip_runtime.h>

#define B_ 4096
#define F_ 26
#define L_ 10
#define V_ 100000
#define D_ 128

typedef __attribute__((ext_vector_type(8))) short short8;
typedef __attribute__((ext_vector_type(4))) float f32x4;

// fp32 -> packed (hi_bf16 << 16) | lo_bf16, both RNE. value ~= hi + lo.
__device__ inline unsigned pack_split(float f) {
    union { float f; unsigned u; } a; a.f = f;
    unsigned r = (a.u + 0x7FFFu + ((a.u >> 16) & 1u)) >> 16;
    union { unsigned u; float f; } hf; hf.u = r << 16;
    float rem = f - hf.f;
    union { float f; unsigned u; } b; b.f = rem;
    unsigned r2 = (b.u + 0x7FFFu + ((b.u >> 16) & 1u)) >> 16;
    return (r << 16) | (r2 & 0xFFFFu);
}
__device__ inline float unpack_f(unsigned u) {
    union { unsigned u; float f; } h; h.u = u & 0xFFFF0000u;
    union { unsigned u; float f; } l; l.u = u << 16;
    return h.f + l.f;
}

// int32 vs int64 indices: wave-parallel probe of odd words.
__device__ __forceinline__ int detect_stride(const int* __restrict__ iw) {
    const int lane = threadIdx.x & 63;
    return __any(iw[1 + 2 * lane] != 0) ? 1 : 2;
}

// One wave: gather-sum bag (s, f) -> bagp[s][f][128] hi/lo packed.
__device__ __forceinline__ void gather_pair(
    const int* __restrict__ idx_words, const float* __restrict__ tables,
    unsigned* __restrict__ bagp, int s, int f, int st)
{
    const int lane = threadIdx.x & 63;
    const float* tab = tables + (size_t)f * V_ * D_;
    const size_t ibase = (size_t)s * (F_ * L_) + (size_t)f * L_;
    float2 a = {0.f, 0.f};
    #pragma unroll
    for (int l = 0; l < L_; ++l) {
        int v = idx_words[(ibase + l) * st];
        v = v < 0 ? 0 : (v >= V_ ? V_ - 1 : v);
        float2 x = *reinterpret_cast<const float2*>(tab + (size_t)v * D_ + 2 * lane);
        a.x += x.x; a.y += x.y;
    }
    uint2 o;
    o.x = pack_split(a.x);
    o.y = pack_split(a.y);
    *reinterpret_cast<uint2*>(bagp + ((size_t)s * F_ + f) * 128 + 2 * lane) = o;
}

// ---- weight transpose+split tile ----
__device__ void prep_tile(const float* __restrict__ W, unsigned* __restrict__ Wt,
                          int K, int N, int Kp, int local)
{
    __shared__ float tile[32][33];
    const int t = threadIdx.x;
    const int tx = t & 31, ty = t >> 5;
    const int nbt = N >> 5;
    const int nb = (local % nbt) << 5, kb = (local / nbt) << 5;
    #pragma unroll
    for (int i = 0; i < 4; ++i) {
        int k = kb + ty + i * 8;
        tile[ty + i * 8][tx] = (k < K) ? W[(size_t)k * N + nb + tx] : 0.f;
    }
    __syncthreads();
    #pragma unroll
    for (int i = 0; i < 4; ++i) {
        int nl = ty + i * 8;
        Wt[(size_t)(nb + nl) * Kp + kb + tx] = pack_split(tile[tx][nl]);
    }
}

// L1: prep (2832 blocks, small LDS) + ALL gather pairs (26624 blocks,
// 4 pairs/block, f-major so concurrent blocks hit ONE 51 MB table -> L3
// captures repeated rows). LDS footprints compatible (no 64 KB gemm LDS).
__global__ __launch_bounds__(256) void prep_gather(
    const float* dW0, const float* dW1, const float* dW2,
    const float* oW0, const float* oW1, const float* oW2, const float* oW3,
    unsigned* dWt0, unsigned* dWt1, unsigned* dWt2,
    unsigned* oWt0, unsigned* oWt1, unsigned* oWt2, unsigned* oWt3,
    const float* dense, unsigned* densep,
    const int* idx_words, const float* tables, unsigned* bagp)
{
    const int bid = blockIdx.x;
    if      (bid < 16)   prep_tile(dW0, dWt0, 13,   512,  32,   bid);
    else if (bid < 144)  prep_tile(dW1, dWt1, 512,  256,  512,  bid - 16);
    else if (bid < 176)  prep_tile(dW2, dWt2, 256,  128,  256,  bid - 144);
    else if (bid < 656)  prep_tile(oW0, oWt0, 479,  1024, 480,  bid - 176);
    else if (bid < 1680) prep_tile(oW1, oWt1, 1024, 1024, 1024, bid - 656);
    else if (bid < 2192) prep_tile(oW2, oWt2, 1024, 512,  1024, bid - 1680);
    else if (bid < 2320) prep_tile(oW3, oWt3, 512,  256,  512,  bid - 2192);
    else if (bid < 2832) {
        int g = (bid - 2320) * 256 + threadIdx.x;   // B*32 slots
        int b = g >> 5, k = g & 31;
        densep[g] = (k < 13) ? pack_split(dense[(size_t)b * 13 + k]) : 0u;
    } else {
        int st = detect_stride(idx_words);
        int g = (bid - 2832) * 4 + (threadIdx.x >> 6);  // 0..106495, f-major
        int f = g >> 12;            // g / 4096
        int s = g & 4095;           // g % 4096
        gather_pair(idx_words, tables, bagp, s, f, st);
    }
}

// C = relu(A @ W + bias), bf16x3 MFMA, 8 waves (2x4), wave-tile 64x32,
// double-buffered LDS (exact round-8/13 structure: best measured).
__global__ __launch_bounds__(512) void gemm8(
    const unsigned* __restrict__ Ap, const unsigned* __restrict__ Wt,
    const float* __restrict__ bias, unsigned* __restrict__ Cp,
    int N, int Kp)
{
    __shared__ __align__(16) unsigned Au[2][128 * 32];
    __shared__ __align__(16) unsigned Bu[2][128 * 32];

    const int t    = threadIdx.x;
    const int lane = t & 63;
    const int w    = t >> 6;
    const int wm   = w >> 2, wn = w & 3;
    const int m0   = blockIdx.y * 128, n0 = blockIdx.x * 128;

    f32x4 acc[4][2];
    const f32x4 zero = {0.f, 0.f, 0.f, 0.f};
    #pragma unroll
    for (int i = 0; i < 4; ++i)
        #pragma unroll
        for (int j = 0; j < 2; ++j) acc[i][j] = zero;

    const unsigned* Ab = Ap + (size_t)m0 * Kp;
    const unsigned* Bb = Wt + (size_t)n0 * Kp;

    const int g4 = lane >> 4;
    const int rr = lane & 15;

    auto STAGE = [&](int buf, int k0) {
        #pragma unroll
        for (int i = 0; i < 2; ++i) {
            int chunk = t + (i << 9);
            int row = chunk >> 3, ch = chunk & 7;
            int sch = ch ^ (row & 7);
            __builtin_amdgcn_global_load_lds(
                (const __attribute__((address_space(1))) unsigned*)(Ab + (size_t)row * Kp + k0 + (sch << 2)),
                &Au[buf][chunk << 2], 16, 0, 0);
        }
        #pragma unroll
        for (int i = 0; i < 2; ++i) {
            int chunk = t + (i << 9);
            int row = chunk >> 3, ch = chunk & 7;
            int sch = ch ^ (row & 7);
            __builtin_amdgcn_global_load_lds(
                (const __attribute__((address_space(1))) unsigned*)(Bb + (size_t)row * Kp + k0 + (sch << 2)),
                &Bu[buf][chunk << 2], 16, 0, 0);
        }
    };

    auto COMPUTE = [&](int buf) {
        const unsigned* au = Au[buf];
        const unsigned* bu = Bu[buf];
        short8 bh[2], bl[2];
        #pragma unroll
        for (int tj = 0; tj < 2; ++tj) {
            int r = wn * 32 + tj * 16 + rr;
            int c0 = (2 * g4) ^ (r & 7), c1 = (2 * g4 + 1) ^ (r & 7);
            uint4 p = *reinterpret_cast<const uint4*>(&bu[r * 32 + (c0 << 2)]);
            uint4 q = *reinterpret_cast<const uint4*>(&bu[r * 32 + (c1 << 2)]);
            union { short8 s; uint4 u; } H, L;
            H.u.x = __builtin_amdgcn_perm(p.y, p.x, 0x07060302u);
            L.u.x = __builtin_amdgcn_perm(p.y, p.x, 0x05040100u);
            H.u.y = __builtin_amdgcn_perm(p.w, p.z, 0x07060302u);
            L.u.y = __builtin_amdgcn_perm(p.w, p.z, 0x05040100u);
            H.u.z = __builtin_amdgcn_perm(q.y, q.x, 0x07060302u);
            L.u.z = __builtin_amdgcn_perm(q.y, q.x, 0x05040100u);
            H.u.w = __builtin_amdgcn_perm(q.w, q.z, 0x07060302u);
            L.u.w = __builtin_amdgcn_perm(q.w, q.z, 0x05040100u);
            bh[tj] = H.s; bl[tj] = L.s;
        }
        #pragma unroll
        for (int ti = 0; ti < 4; ++ti) {
            int r = wm * 64 + ti * 16 + rr;
            int c0 = (2 * g4) ^ (r & 7), c1 = (2 * g4 + 1) ^ (r & 7);
            uint4 p = *reinterpret_cast<const uint4*>(&au[r * 32 + (c0 << 2)]);
            uint4 q = *reinterpret_cast<const uint4*>(&au[r * 32 + (c1 << 2)]);
            union { short8 s; uint4 u; } H, L;
            H.u.x = __builtin_amdgcn_perm(p.y, p.x, 0x07060302u);
            L.u.x = __builtin_amdgcn_perm(p.y, p.x, 0x05040100u);
            H.u.y = __builtin_amdgcn_perm(p.w, p.z, 0x07060302u);
            L.u.y = __builtin_amdgcn_perm(p.w, p.z, 0x05040100u);
            H.u.z = __builtin_amdgcn_perm(q.y, q.x, 0x07060302u);
            L.u.z = __builtin_amdgcn_perm(q.y, q.x, 0x05040100u);
            H.u.w = __builtin_amdgcn_perm(q.w, q.z, 0x07060302u);
            L.u.w = __builtin_amdgcn_perm(q.w, q.z, 0x05040100u);
            short8 ah = H.s, al = L.s;
            #pragma unroll
            for (int tj = 0; tj < 2; ++tj) {
                f32x4 c = acc[ti][tj];
                c = __builtin_amdgcn_mfma_f32_16x16x32_bf16(ah, bh[tj], c, 0, 0, 0);
                c = __builtin_amdgcn_mfma_f32_16x16x32_bf16(ah, bl[tj], c, 0, 0, 0);
                c = __builtin_amdgcn_mfma_f32_16x16x32_bf16(al, bh[tj], c, 0, 0, 0);
                acc[ti][tj] = c;
            }
        }
    };

    const int nt = Kp >> 5;
    STAGE(0, 0);
    __syncthreads();
    int cur = 0;
    for (int ts = 0; ts < nt - 1; ++ts) {
        STAGE(cur ^ 1, (ts + 1) << 5);
        COMPUTE(cur);
        __syncthreads();
        cur ^= 1;
    }
    COMPUTE(cur);

    #pragma unroll
    for (int ti = 0; ti < 4; ++ti) {
        int row = m0 + wm * 64 + ti * 16 + (g4 << 2);
        #pragma unroll
        for (int tj = 0; tj < 2; ++tj) {
            int col = n0 + wn * 32 + tj * 16 + rr;
            float bv = bias[col];
            #pragma unroll
            for (int r = 0; r < 4; ++r) {
                float v = fmaxf(acc[ti][tj][r] + bv, 0.f);
                Cp[(size_t)(row + r) * N + col] = pack_split(v);
            }
        }
    }
}

// 4 samples per block, one wave per sample: stream bagp rows + x2p into LDS
// hi/lo planes (XOR chunk-swizzled), 27x27 Gram via bf16x3 MFMA, write feats.
__global__ __launch_bounds__(256) void interact_mfma(
    const unsigned* __restrict__ x2p,      // [B,128] packed
    const unsigned* __restrict__ bagp,     // [B,26,128] packed
    unsigned*       __restrict__ featsp)   // [B,480] packed
{
    __shared__ unsigned zh[4][32][64];
    __shared__ unsigned zl[4][32][64];

    const int t    = threadIdx.x;
    const int w    = t >> 6;
    const int lane = t & 63;
    const int s    = blockIdx.x * 4 + w;   // sample

    uint2 xv = *reinterpret_cast<const uint2*>(x2p + (size_t)s * 128 + 2 * lane);
    *reinterpret_cast<uint2*>(featsp + (size_t)s * 480 + 2 * lane) = xv;
    if (lane == 0) featsp[(size_t)s * 480 + 479] = 0u;
    zh[w][0][lane] = (xv.x >> 16) | (xv.y & 0xFFFF0000u);
    zl[w][0][lane] = (xv.x & 0xFFFFu) | (xv.y << 16);

    for (int f = 0; f < F_; ++f) {
        uint2 u = *reinterpret_cast<const uint2*>(bagp + ((size_t)s * F_ + f) * 128 + 2 * lane);
        int r  = f + 1;
        int dw = (((lane >> 2) ^ (r & 7)) << 2) + (lane & 3);  // chunk-swizzled dword
        zh[w][r][dw] = (u.x >> 16) | (u.y & 0xFFFF0000u);
        zl[w][r][dw] = (u.x & 0xFFFFu) | (u.y << 16);
    }
    __syncthreads();

    const int g4 = lane >> 4;
    const int rr = lane & 15;
    f32x4 acc[2][2];
    const f32x4 zero = {0.f, 0.f, 0.f, 0.f};
    acc[0][0] = zero; acc[0][1] = zero; acc[1][0] = zero; acc[1][1] = zero;

    #pragma unroll
    for (int ks = 0; ks < 4; ++ks) {
        short8 h[2], lo[2];
        #pragma unroll
        for (int mi = 0; mi < 2; ++mi) {
            int r = mi * 16 + rr;
            int c = (ks * 4 + g4) ^ (r & 7);
            h[mi]  = *reinterpret_cast<const short8*>(&zh[w][r][c << 2]);
            lo[mi] = *reinterpret_cast<const short8*>(&zl[w][r][c << 2]);
        }
        #pragma unroll
        for (int mi = 0; mi < 2; ++mi)
            #pragma unroll
            for (int nj = 0; nj < 2; ++nj) {
                f32x4 c = acc[mi][nj];
                c = __builtin_amdgcn_mfma_f32_16x16x32_bf16(h[mi],  h[nj],  c, 0, 0, 0);
                c = __builtin_amdgcn_mfma_f32_16x16x32_bf16(h[mi],  lo[nj], c, 0, 0, 0);
                c = __builtin_amdgcn_mfma_f32_16x16x32_bf16(lo[mi], h[nj],  c, 0, 0, 0);
                acc[mi][nj] = c;
            }
    }

    #pragma unroll
    for (int mi = 0; mi < 2; ++mi) {
        #pragma unroll
        for (int nj = 0; nj < 2; ++nj) {
            #pragma unroll
            for (int r = 0; r < 4; ++r) {
                int i = mi * 16 + g4 * 4 + r;
                int j = nj * 16 + rr;
                if (i < j && j <= 26) {
                    int p = i * 26 - (i * (i - 1)) / 2 + (j - i - 1);
                    featsp[(size_t)s * 480 + 128 + p] = pack_split(acc[mi][nj][r]);
                }
            }
        }
    }
}

// logits[b] = dot(unpack(y3p[b,:256]), w) + bias
__global__ __launch_bounds__(256) void final_dot(
    const unsigned* __restrict__ yp, const float* __restrict__ w,
    const float* __restrict__ bias, float* __restrict__ out)
{
    const int wave = threadIdx.x >> 6;
    const int lane = threadIdx.x & 63;
    const int b = blockIdx.x * 4 + wave;
    uint4 u = *reinterpret_cast<const uint4*>(yp + (size_t)b * 256 + lane * 4);
    float4 wv = *reinterpret_cast<const float4*>(&w[lane * 4]);
    float s = unpack_f(u.x) * wv.x + unpack_f(u.y) * wv.y +
              unpack_f(u.z) * wv.z + unpack_f(u.w) * wv.w;
    #pragma unroll
    for (int off = 32; off; off >>= 1) s += __shfl_xor(s, off);
    if (lane == 0) out[b] = s + bias[0];
}

extern "C" void kernel_launch(void* const* d_in, const int* in_sizes, int n_in,
                              void* d_out, int out_size, void* d_ws, size_t ws_size,
                              hipStream_t stream)
{
    const float* dense   = (const float*)d_in[0];
    const int*   indices = (const int*)  d_in[1];
    const float* tables  = (const float*)d_in[2];
    const float* dW0 = (const float*)d_in[3];  const float* db0 = (const float*)d_in[4];
    const float* dW1 = (const float*)d_in[5];  const float* db1 = (const float*)d_in[6];
    const float* dW2 = (const float*)d_in[7];  const float* db2 = (const float*)d_in[8];
    const float* oW0 = (const float*)d_in[9];  const float* ob0 = (const float*)d_in[10];
    const float* oW1 = (const float*)d_in[11]; const float* ob1 = (const float*)d_in[12];
    const float* oW2 = (const float*)d_in[13]; const float* ob2 = (const float*)d_in[14];
    const float* oW3 = (const float*)d_in[15]; const float* ob3 = (const float*)d_in[16];
    const float* oW4 = (const float*)d_in[17]; const float* ob4 = (const float*)d_in[18];
    float* out = (float*)d_out;

    unsigned* wsu = (unsigned*)d_ws;
    unsigned* dWt0 = wsu + 0;          // [512][32]
    unsigned* dWt1 = wsu + 16384;      // [256][512]
    unsigned* dWt2 = wsu + 147456;     // [128][256]
    unsigned* oWt0 = wsu + 180224;     // [1024][480]
    unsigned* oWt1 = wsu + 671744;     // [1024][1024]
    unsigned* oWt2 = wsu + 1720320;    // [512][1024]
    unsigned* oWt3 = wsu + 2244608;    // [256][512]
    unsigned* densep = wsu + 2375680;  // [4096][32]
    unsigned* x2p    = wsu + 2506752;  // [4096][128]
    unsigned* featsp = wsu + 3031040;  // [4096][480]
    unsigned* x0p    = wsu + 5000000;  // [4096][512]
    unsigned* x1p    = wsu + 7097152;  // [4096][256]
    unsigned* y0p    = wsu + 5000000;  // [4096][1024] (x0p/x1p dead)
    unsigned* y1p    = wsu + 9194304;  // [4096][1024]
    unsigned* y2p    = wsu + 2506752;  // [4096][512]  (x2p/featsp dead)
    unsigned* y3p    = wsu + 5000000;  // [4096][256]  (y0p dead)
    unsigned* bagp   = wsu + 13500000; // [4096][26][128]
    // high water ~108.5 MB

    // L1: prep + entire gather (f-major for L3 row-reuse), one launch
    prep_gather<<<2832 + 26624, 256, 0, stream>>>(
        dW0, dW1, dW2, oW0, oW1, oW2, oW3,
        dWt0, dWt1, dWt2, oWt0, oWt1, oWt2, oWt3,
        dense, densep, indices, tables, bagp);

    // bottom MLP
    gemm8<<<dim3(4, 32), 512, 0, stream>>>(densep, dWt0, db0, x0p, 512, 32);
    gemm8<<<dim3(2, 32), 512, 0, stream>>>(x0p,    dWt1, db1, x1p, 256, 512);
    gemm8<<<dim3(1, 32), 512, 0, stream>>>(x1p,    dWt2, db2, x2p, 128, 256);

    interact_mfma<<<B_ / 4, 256, 0, stream>>>(x2p, bagp, featsp);

    // over MLP
    gemm8<<<dim3(8, 32), 512, 0, stream>>>(featsp, oWt0, ob0, y0p, 1024, 480);
    gemm8<<<dim3(8, 32), 512, 0, stream>>>(y0p,    oWt1, ob1, y1p, 1024, 1024);
    gemm8<<<dim3(4, 32), 512, 0, stream>>>(y1p,    oWt2, ob2, y2p, 512, 1024);
    gemm8<<<dim3(2, 32), 512, 0, stream>>>(y2p,    oWt3, ob3, y3p, 256, 512);

    final_dot<<<B_ / 4, 256, 0, stream>>>(y3p, oW4, ob4, out);
}

// Round 16
// 302.229 us; speedup vs baseline: 1.0704x; 1.0704x over previous
//
#include <hip/hip_runtime.h>

#define B_ 4096
#define F_ 26
#define L_ 10
#define V_ 100000
#define D_ 128

typedef __attribute__((ext_vector_type(8))) short short8;
typedef __attribute__((ext_vector_type(4))) float f32x4;

// fp32 -> packed (hi_bf16 << 16) | lo_bf16, both RNE. value ~= hi + lo.
__device__ inline unsigned pack_split(float f) {
    union { float f; unsigned u; } a; a.f = f;
    unsigned r = (a.u + 0x7FFFu + ((a.u >> 16) & 1u)) >> 16;
    union { unsigned u; float f; } hf; hf.u = r << 16;
    float rem = f - hf.f;
    union { float f; unsigned u; } b; b.f = rem;
    unsigned r2 = (b.u + 0x7FFFu + ((b.u >> 16) & 1u)) >> 16;
    return (r << 16) | (r2 & 0xFFFFu);
}
__device__ inline float unpack_f(unsigned u) {
    union { unsigned u; float f; } h; h.u = u & 0xFFFF0000u;
    union { unsigned u; float f; } l; l.u = u << 16;
    return h.f + l.f;
}

// int32 vs int64 indices: wave-parallel probe of odd words.
__device__ __forceinline__ int detect_stride(const int* __restrict__ iw) {
    const int lane = threadIdx.x & 63;
    return __any(iw[1 + 2 * lane] != 0) ? 1 : 2;
}

// One wave: gather-sum bag (s, f) -> bagp[s][f][128] hi/lo packed.
__device__ __forceinline__ void gather_pair(
    const int* __restrict__ idx_words, const float* __restrict__ tables,
    unsigned* __restrict__ bagp, int s, int f, int st)
{
    const int lane = threadIdx.x & 63;
    const float* tab = tables + (size_t)f * V_ * D_;
    const size_t ibase = (size_t)s * (F_ * L_) + (size_t)f * L_;
    float2 a = {0.f, 0.f};
    #pragma unroll
    for (int l = 0; l < L_; ++l) {
        int v = idx_words[(ibase + l) * st];
        v = v < 0 ? 0 : (v >= V_ ? V_ - 1 : v);
        float2 x = *reinterpret_cast<const float2*>(tab + (size_t)v * D_ + 2 * lane);
        a.x += x.x; a.y += x.y;
    }
    uint2 o;
    o.x = pack_split(a.x);
    o.y = pack_split(a.y);
    *reinterpret_cast<uint2*>(bagp + ((size_t)s * F_ + f) * 128 + 2 * lane) = o;
}

// ---- weight transpose+split tile ----
__device__ void prep_tile(const float* __restrict__ W, unsigned* __restrict__ Wt,
                          int K, int N, int Kp, int local)
{
    __shared__ float tile[32][33];
    const int t = threadIdx.x;
    const int tx = t & 31, ty = t >> 5;
    const int nbt = N >> 5;
    const int nb = (local % nbt) << 5, kb = (local / nbt) << 5;
    #pragma unroll
    for (int i = 0; i < 4; ++i) {
        int k = kb + ty + i * 8;
        tile[ty + i * 8][tx] = (k < K) ? W[(size_t)k * N + nb + tx] : 0.f;
    }
    __syncthreads();
    #pragma unroll
    for (int i = 0; i < 4; ++i) {
        int nl = ty + i * 8;
        Wt[(size_t)(nb + nl) * Kp + kb + tx] = pack_split(tile[tx][nl]);
    }
}

// ONE WAVE PER (sample, bag), s-major (r13 ordering: contiguous bagp writes).
__global__ __launch_bounds__(256) void gather_bags(
    const int*   __restrict__ idx_words,
    const float* __restrict__ tables,
    unsigned*    __restrict__ bagp)
{
    const int g = blockIdx.x * 4 + (threadIdx.x >> 6);
    const int s = g / F_;
    const int f = g - s * F_;
    int st = detect_stride(idx_words);
    gather_pair(idx_words, tables, bagp, s, f, st);
}

__global__ __launch_bounds__(256) void prep_all(
    const float* dW0, const float* dW1, const float* dW2,
    const float* oW0, const float* oW1, const float* oW2, const float* oW3,
    unsigned* dWt0, unsigned* dWt1, unsigned* dWt2,
    unsigned* oWt0, unsigned* oWt1, unsigned* oWt2, unsigned* oWt3,
    const float* dense, unsigned* densep)
{
    const int bid = blockIdx.x;
    if      (bid < 16)   prep_tile(dW0, dWt0, 13,   512,  32,   bid);
    else if (bid < 144)  prep_tile(dW1, dWt1, 512,  256,  512,  bid - 16);
    else if (bid < 176)  prep_tile(dW2, dWt2, 256,  128,  256,  bid - 144);
    else if (bid < 656)  prep_tile(oW0, oWt0, 479,  1024, 480,  bid - 176);
    else if (bid < 1680) prep_tile(oW1, oWt1, 1024, 1024, 1024, bid - 656);
    else if (bid < 2192) prep_tile(oW2, oWt2, 1024, 512,  1024, bid - 1680);
    else if (bid < 2320) prep_tile(oW3, oWt3, 512,  256,  512,  bid - 2192);
    else {
        int g = (bid - 2320) * 256 + threadIdx.x;   // B*32 slots
        int b = g >> 5, k = g & 31;
        densep[g] = (k < 13) ? pack_split(dense[(size_t)b * 13 + k]) : 0u;
    }
}

// TM=128 GEMM: 8 waves (2x4), wave-tile 64x32, dbuf LDS (r8/r13 structure).
__global__ __launch_bounds__(512) void gemm8(
    const unsigned* __restrict__ Ap, const unsigned* __restrict__ Wt,
    const float* __restrict__ bias, unsigned* __restrict__ Cp,
    int N, int Kp)
{
    __shared__ __align__(16) unsigned Au[2][128 * 32];
    __shared__ __align__(16) unsigned Bu[2][128 * 32];

    const int t    = threadIdx.x;
    const int lane = t & 63;
    const int w    = t >> 6;
    const int wm   = w >> 2, wn = w & 3;
    const int m0   = blockIdx.y * 128, n0 = blockIdx.x * 128;

    f32x4 acc[4][2];
    const f32x4 zero = {0.f, 0.f, 0.f, 0.f};
    #pragma unroll
    for (int i = 0; i < 4; ++i)
        #pragma unroll
        for (int j = 0; j < 2; ++j) acc[i][j] = zero;

    const unsigned* Ab = Ap + (size_t)m0 * Kp;
    const unsigned* Bb = Wt + (size_t)n0 * Kp;

    const int g4 = lane >> 4;
    const int rr = lane & 15;

    auto STAGE = [&](int buf, int k0) {
        #pragma unroll
        for (int i = 0; i < 2; ++i) {
            int chunk = t + (i << 9);
            int row = chunk >> 3, ch = chunk & 7;
            int sch = ch ^ (row & 7);
            __builtin_amdgcn_global_load_lds(
                (const __attribute__((address_space(1))) unsigned*)(Ab + (size_t)row * Kp + k0 + (sch << 2)),
                &Au[buf][chunk << 2], 16, 0, 0);
        }
        #pragma unroll
        for (int i = 0; i < 2; ++i) {
            int chunk = t + (i << 9);
            int row = chunk >> 3, ch = chunk & 7;
            int sch = ch ^ (row & 7);
            __builtin_amdgcn_global_load_lds(
                (const __attribute__((address_space(1))) unsigned*)(Bb + (size_t)row * Kp + k0 + (sch << 2)),
                &Bu[buf][chunk << 2], 16, 0, 0);
        }
    };

    auto COMPUTE = [&](int buf) {
        const unsigned* au = Au[buf];
        const unsigned* bu = Bu[buf];
        short8 bh[2], bl[2];
        #pragma unroll
        for (int tj = 0; tj < 2; ++tj) {
            int r = wn * 32 + tj * 16 + rr;
            int c0 = (2 * g4) ^ (r & 7), c1 = (2 * g4 + 1) ^ (r & 7);
            uint4 p = *reinterpret_cast<const uint4*>(&bu[r * 32 + (c0 << 2)]);
            uint4 q = *reinterpret_cast<const uint4*>(&bu[r * 32 + (c1 << 2)]);
            union { short8 s; uint4 u; } H, L;
            H.u.x = __builtin_amdgcn_perm(p.y, p.x, 0x07060302u);
            L.u.x = __builtin_amdgcn_perm(p.y, p.x, 0x05040100u);
            H.u.y = __builtin_amdgcn_perm(p.w, p.z, 0x07060302u);
            L.u.y = __builtin_amdgcn_perm(p.w, p.z, 0x05040100u);
            H.u.z = __builtin_amdgcn_perm(q.y, q.x, 0x07060302u);
            L.u.z = __builtin_amdgcn_perm(q.y, q.x, 0x05040100u);
            H.u.w = __builtin_amdgcn_perm(q.w, q.z, 0x07060302u);
            L.u.w = __builtin_amdgcn_perm(q.w, q.z, 0x05040100u);
            bh[tj] = H.s; bl[tj] = L.s;
        }
        #pragma unroll
        for (int ti = 0; ti < 4; ++ti) {
            int r = wm * 64 + ti * 16 + rr;
            int c0 = (2 * g4) ^ (r & 7), c1 = (2 * g4 + 1) ^ (r & 7);
            uint4 p = *reinterpret_cast<const uint4*>(&au[r * 32 + (c0 << 2)]);
            uint4 q = *reinterpret_cast<const uint4*>(&au[r * 32 + (c1 << 2)]);
            union { short8 s; uint4 u; } H, L;
            H.u.x = __builtin_amdgcn_perm(p.y, p.x, 0x07060302u);
            L.u.x = __builtin_amdgcn_perm(p.y, p.x, 0x05040100u);
            H.u.y = __builtin_amdgcn_perm(p.w, p.z, 0x07060302u);
            L.u.y = __builtin_amdgcn_perm(p.w, p.z, 0x05040100u);
            H.u.z = __builtin_amdgcn_perm(q.y, q.x, 0x07060302u);
            L.u.z = __builtin_amdgcn_perm(q.y, q.x, 0x05040100u);
            H.u.w = __builtin_amdgcn_perm(q.w, q.z, 0x07060302u);
            L.u.w = __builtin_amdgcn_perm(q.w, q.z, 0x05040100u);
            short8 ah = H.s, al = L.s;
            #pragma unroll
            for (int tj = 0; tj < 2; ++tj) {
                f32x4 c = acc[ti][tj];
                c = __builtin_amdgcn_mfma_f32_16x16x32_bf16(ah, bh[tj], c, 0, 0, 0);
                c = __builtin_amdgcn_mfma_f32_16x16x32_bf16(ah, bl[tj], c, 0, 0, 0);
                c = __builtin_amdgcn_mfma_f32_16x16x32_bf16(al, bh[tj], c, 0, 0, 0);
                acc[ti][tj] = c;
            }
        }
    };

    const int nt = Kp >> 5;
    STAGE(0, 0);
    __syncthreads();
    int cur = 0;
    for (int ts = 0; ts < nt - 1; ++ts) {
        STAGE(cur ^ 1, (ts + 1) << 5);
        COMPUTE(cur);
        __syncthreads();
        cur ^= 1;
    }
    COMPUTE(cur);

    #pragma unroll
    for (int ti = 0; ti < 4; ++ti) {
        int row = m0 + wm * 64 + ti * 16 + (g4 << 2);
        #pragma unroll
        for (int tj = 0; tj < 2; ++tj) {
            int col = n0 + wn * 32 + tj * 16 + rr;
            float bv = bias[col];
            #pragma unroll
            for (int r = 0; r < 4; ++r) {
                float v = fmaxf(acc[ti][tj][r] + bv, 0.f);
                Cp[(size_t)(row + r) * N + col] = pack_split(v);
            }
        }
    }
}

// TM=64 GEMM: 4 waves (1x4), wave-tile 64x32, 48 KB LDS -> 3 blocks/CU.
// Doubles over-MLP grids so cross-block overlap hides stage/drain.
// Same K-loop order as gemm8 -> bit-identical results.
__global__ __launch_bounds__(256) void gemm4(
    const unsigned* __restrict__ Ap, const unsigned* __restrict__ Wt,
    const float* __restrict__ bias, unsigned* __restrict__ Cp,
    int N, int Kp)
{
    __shared__ __align__(16) unsigned Au[2][64 * 32];    // 16 KB
    __shared__ __align__(16) unsigned Bu[2][128 * 32];   // 32 KB

    const int t    = threadIdx.x;
    const int lane = t & 63;
    const int wn   = t >> 6;                   // 0..3
    const int m0   = blockIdx.y * 64, n0 = blockIdx.x * 128;

    f32x4 acc[4][2];
    const f32x4 zero = {0.f, 0.f, 0.f, 0.f};
    #pragma unroll
    for (int i = 0; i < 4; ++i)
        #pragma unroll
        for (int j = 0; j < 2; ++j) acc[i][j] = zero;

    const unsigned* Ab = Ap + (size_t)m0 * Kp;
    const unsigned* Bb = Wt + (size_t)n0 * Kp;

    const int g4 = lane >> 4;
    const int rr = lane & 15;

    auto STAGE = [&](int buf, int k0) {
        #pragma unroll
        for (int i = 0; i < 2; ++i) {              // A: 512 chunks
            int chunk = t + (i << 8);
            int row = chunk >> 3, ch = chunk & 7;
            int sch = ch ^ (row & 7);
            __builtin_amdgcn_global_load_lds(
                (const __attribute__((address_space(1))) unsigned*)(Ab + (size_t)row * Kp + k0 + (sch << 2)),
                &Au[buf][chunk << 2], 16, 0, 0);
        }
        #pragma unroll
        for (int i = 0; i < 4; ++i) {              // B: 1024 chunks
            int chunk = t + (i << 8);
            int row = chunk >> 3, ch = chunk & 7;
            int sch = ch ^ (row & 7);
            __builtin_amdgcn_global_load_lds(
                (const __attribute__((address_space(1))) unsigned*)(Bb + (size_t)row * Kp + k0 + (sch << 2)),
                &Bu[buf][chunk << 2], 16, 0, 0);
        }
    };

    auto COMPUTE = [&](int buf) {
        const unsigned* au = Au[buf];
        const unsigned* bu = Bu[buf];
        short8 bh[2], bl[2];
        #pragma unroll
        for (int tj = 0; tj < 2; ++tj) {
            int r = wn * 32 + tj * 16 + rr;
            int c0 = (2 * g4) ^ (r & 7), c1 = (2 * g4 + 1) ^ (r & 7);
            uint4 p = *reinterpret_cast<const uint4*>(&bu[r * 32 + (c0 << 2)]);
            uint4 q = *reinterpret_cast<const uint4*>(&bu[r * 32 + (c1 << 2)]);
            union { short8 s; uint4 u; } H, L;
            H.u.x = __builtin_amdgcn_perm(p.y, p.x, 0x07060302u);
            L.u.x = __builtin_amdgcn_perm(p.y, p.x, 0x05040100u);
            H.u.y = __builtin_amdgcn_perm(p.w, p.z, 0x07060302u);
            L.u.y = __builtin_amdgcn_perm(p.w, p.z, 0x05040100u);
            H.u.z = __builtin_amdgcn_perm(q.y, q.x, 0x07060302u);
            L.u.z = __builtin_amdgcn_perm(q.y, q.x, 0x05040100u);
            H.u.w = __builtin_amdgcn_perm(q.w, q.z, 0x07060302u);
            L.u.w = __builtin_amdgcn_perm(q.w, q.z, 0x05040100u);
            bh[tj] = H.s; bl[tj] = L.s;
        }
        #pragma unroll
        for (int ti = 0; ti < 4; ++ti) {
            int r = ti * 16 + rr;                  // 64 A-rows
            int c0 = (2 * g4) ^ (r & 7), c1 = (2 * g4 + 1) ^ (r & 7);
            uint4 p = *reinterpret_cast<const uint4*>(&au[r * 32 + (c0 << 2)]);
            uint4 q = *reinterpret_cast<const uint4*>(&au[r * 32 + (c1 << 2)]);
            union { short8 s; uint4 u; } H, L;
            H.u.x = __builtin_amdgcn_perm(p.y, p.x, 0x07060302u);
            L.u.x = __builtin_amdgcn_perm(p.y, p.x, 0x05040100u);
            H.u.y = __builtin_amdgcn_perm(p.w, p.z, 0x07060302u);
            L.u.y = __builtin_amdgcn_perm(p.w, p.z, 0x05040100u);
            H.u.z = __builtin_amdgcn_perm(q.y, q.x, 0x07060302u);
            L.u.z = __builtin_amdgcn_perm(q.y, q.x, 0x05040100u);
            H.u.w = __builtin_amdgcn_perm(q.w, q.z, 0x07060302u);
            L.u.w = __builtin_amdgcn_perm(q.w, q.z, 0x05040100u);
            short8 ah = H.s, al = L.s;
            #pragma unroll
            for (int tj = 0; tj < 2; ++tj) {
                f32x4 c = acc[ti][tj];
                c = __builtin_amdgcn_mfma_f32_16x16x32_bf16(ah, bh[tj], c, 0, 0, 0);
                c = __builtin_amdgcn_mfma_f32_16x16x32_bf16(ah, bl[tj], c, 0, 0, 0);
                c = __builtin_amdgcn_mfma_f32_16x16x32_bf16(al, bh[tj], c, 0, 0, 0);
                acc[ti][tj] = c;
            }
        }
    };

    const int nt = Kp >> 5;
    STAGE(0, 0);
    __syncthreads();
    int cur = 0;
    for (int ts = 0; ts < nt - 1; ++ts) {
        STAGE(cur ^ 1, (ts + 1) << 5);
        COMPUTE(cur);
        __syncthreads();
        cur ^= 1;
    }
    COMPUTE(cur);

    #pragma unroll
    for (int ti = 0; ti < 4; ++ti) {
        int row = m0 + ti * 16 + (g4 << 2);
        #pragma unroll
        for (int tj = 0; tj < 2; ++tj) {
            int col = n0 + wn * 32 + tj * 16 + rr;
            float bv = bias[col];
            #pragma unroll
            for (int r = 0; r < 4; ++r) {
                float v = fmaxf(acc[ti][tj][r] + bv, 0.f);
                Cp[(size_t)(row + r) * N + col] = pack_split(v);
            }
        }
    }
}

// 4 samples per block, one wave per sample (r13, unchanged).
__global__ __launch_bounds__(256) void interact_mfma(
    const unsigned* __restrict__ x2p,
    const unsigned* __restrict__ bagp,
    unsigned*       __restrict__ featsp)
{
    __shared__ unsigned zh[4][32][64];
    __shared__ unsigned zl[4][32][64];

    const int t    = threadIdx.x;
    const int w    = t >> 6;
    const int lane = t & 63;
    const int s    = blockIdx.x * 4 + w;

    uint2 xv = *reinterpret_cast<const uint2*>(x2p + (size_t)s * 128 + 2 * lane);
    *reinterpret_cast<uint2*>(featsp + (size_t)s * 480 + 2 * lane) = xv;
    if (lane == 0) featsp[(size_t)s * 480 + 479] = 0u;
    zh[w][0][lane] = (xv.x >> 16) | (xv.y & 0xFFFF0000u);
    zl[w][0][lane] = (xv.x & 0xFFFFu) | (xv.y << 16);

    for (int f = 0; f < F_; ++f) {
        uint2 u = *reinterpret_cast<const uint2*>(bagp + ((size_t)s * F_ + f) * 128 + 2 * lane);
        int r  = f + 1;
        int dw = (((lane >> 2) ^ (r & 7)) << 2) + (lane & 3);
        zh[w][r][dw] = (u.x >> 16) | (u.y & 0xFFFF0000u);
        zl[w][r][dw] = (u.x & 0xFFFFu) | (u.y << 16);
    }
    __syncthreads();

    const int g4 = lane >> 4;
    const int rr = lane & 15;
    f32x4 acc[2][2];
    const f32x4 zero = {0.f, 0.f, 0.f, 0.f};
    acc[0][0] = zero; acc[0][1] = zero; acc[1][0] = zero; acc[1][1] = zero;

    #pragma unroll
    for (int ks = 0; ks < 4; ++ks) {
        short8 h[2], lo[2];
        #pragma unroll
        for (int mi = 0; mi < 2; ++mi) {
            int r = mi * 16 + rr;
            int c = (ks * 4 + g4) ^ (r & 7);
            h[mi]  = *reinterpret_cast<const short8*>(&zh[w][r][c << 2]);
            lo[mi] = *reinterpret_cast<const short8*>(&zl[w][r][c << 2]);
        }
        #pragma unroll
        for (int mi = 0; mi < 2; ++mi)
            #pragma unroll
            for (int nj = 0; nj < 2; ++nj) {
                f32x4 c = acc[mi][nj];
                c = __builtin_amdgcn_mfma_f32_16x16x32_bf16(h[mi],  h[nj],  c, 0, 0, 0);
                c = __builtin_amdgcn_mfma_f32_16x16x32_bf16(h[mi],  lo[nj], c, 0, 0, 0);
                c = __builtin_amdgcn_mfma_f32_16x16x32_bf16(lo[mi], h[nj],  c, 0, 0, 0);
                acc[mi][nj] = c;
            }
    }

    #pragma unroll
    for (int mi = 0; mi < 2; ++mi) {
        #pragma unroll
        for (int nj = 0; nj < 2; ++nj) {
            #pragma unroll
            for (int r = 0; r < 4; ++r) {
                int i = mi * 16 + g4 * 4 + r;
                int j = nj * 16 + rr;
                if (i < j && j <= 26) {
                    int p = i * 26 - (i * (i - 1)) / 2 + (j - i - 1);
                    featsp[(size_t)s * 480 + 128 + p] = pack_split(acc[mi][nj][r]);
                }
            }
        }
    }
}

// logits[b] = dot(unpack(y3p[b,:256]), w) + bias
__global__ __launch_bounds__(256) void final_dot(
    const unsigned* __restrict__ yp, const float* __restrict__ w,
    const float* __restrict__ bias, float* __restrict__ out)
{
    const int wave = threadIdx.x >> 6;
    const int lane = threadIdx.x & 63;
    const int b = blockIdx.x * 4 + wave;
    uint4 u = *reinterpret_cast<const uint4*>(yp + (size_t)b * 256 + lane * 4);
    float4 wv = *reinterpret_cast<const float4*>(&w[lane * 4]);
    float s = unpack_f(u.x) * wv.x + unpack_f(u.y) * wv.y +
              unpack_f(u.z) * wv.z + unpack_f(u.w) * wv.w;
    #pragma unroll
    for (int off = 32; off; off >>= 1) s += __shfl_xor(s, off);
    if (lane == 0) out[b] = s + bias[0];
}

extern "C" void kernel_launch(void* const* d_in, const int* in_sizes, int n_in,
                              void* d_out, int out_size, void* d_ws, size_t ws_size,
                              hipStream_t stream)
{
    const float* dense   = (const float*)d_in[0];
    const int*   indices = (const int*)  d_in[1];
    const float* tables  = (const float*)d_in[2];
    const float* dW0 = (const float*)d_in[3];  const float* db0 = (const float*)d_in[4];
    const float* dW1 = (const float*)d_in[5];  const float* db1 = (const float*)d_in[6];
    const float* dW2 = (const float*)d_in[7];  const float* db2 = (const float*)d_in[8];
    const float* oW0 = (const float*)d_in[9];  const float* ob0 = (const float*)d_in[10];
    const float* oW1 = (const float*)d_in[11]; const float* ob1 = (const float*)d_in[12];
    const float* oW2 = (const float*)d_in[13]; const float* ob2 = (const float*)d_in[14];
    const float* oW3 = (const float*)d_in[15]; const float* ob3 = (const float*)d_in[16];
    const float* oW4 = (const float*)d_in[17]; const float* ob4 = (const float*)d_in[18];
    float* out = (float*)d_out;

    unsigned* wsu = (unsigned*)d_ws;
    unsigned* dWt0 = wsu + 0;          // [512][32]
    unsigned* dWt1 = wsu + 16384;      // [256][512]
    unsigned* dWt2 = wsu + 147456;     // [128][256]
    unsigned* oWt0 = wsu + 180224;     // [1024][480]
    unsigned* oWt1 = wsu + 671744;     // [1024][1024]
    unsigned* oWt2 = wsu + 1720320;    // [512][1024]
    unsigned* oWt3 = wsu + 2244608;    // [256][512]
    unsigned* densep = wsu + 2375680;  // [4096][32]
    unsigned* x2p    = wsu + 2506752;  // [4096][128]
    unsigned* featsp = wsu + 3031040;  // [4096][480]
    unsigned* x0p    = wsu + 5000000;  // [4096][512]
    unsigned* x1p    = wsu + 7097152;  // [4096][256]
    unsigned* y0p    = wsu + 5000000;  // [4096][1024] (x0p/x1p dead)
    unsigned* y1p    = wsu + 9194304;  // [4096][1024]
    unsigned* y2p    = wsu + 2506752;  // [4096][512]  (x2p/featsp dead)
    unsigned* y3p    = wsu + 5000000;  // [4096][256]  (y0p dead)
    unsigned* bagp   = wsu + 13500000; // [4096][26][128]
    // high water ~108.5 MB

    // r13 launch order: gather first, then prep, bottom MLP, interact, over.
    gather_bags<<<(B_ * F_) / 4, 256, 0, stream>>>(indices, tables, bagp);

    prep_all<<<2832, 256, 0, stream>>>(dW0, dW1, dW2, oW0, oW1, oW2, oW3,
                                       dWt0, dWt1, dWt2, oWt0, oWt1, oWt2, oWt3,
                                       dense, densep);

    gemm8<<<dim3(4, 32), 512, 0, stream>>>(densep, dWt0, db0, x0p, 512, 32);
    gemm8<<<dim3(2, 32), 512, 0, stream>>>(x0p,    dWt1, db1, x1p, 256, 512);
    gemm8<<<dim3(1, 32), 512, 0, stream>>>(x1p,    dWt2, db2, x2p, 128, 256);

    interact_mfma<<<B_ / 4, 256, 0, stream>>>(x2p, bagp, featsp);

    // over MLP: TM=64 variant -> grids 512/512/256/128, 3 blocks/CU
    gemm4<<<dim3(8, 64), 256, 0, stream>>>(featsp, oWt0, ob0, y0p, 1024, 480);
    gemm4<<<dim3(8, 64), 256, 0, stream>>>(y0p,    oWt1, ob1, y1p, 1024, 1024);
    gemm4<<<dim3(4, 64), 256, 0, stream>>>(y1p,    oWt2, ob2, y2p, 512, 1024);
    gemm4<<<dim3(2, 64), 256, 0, stream>>>(y2p,    oWt3, ob3, y3p, 256, 512);

    final_dot<<<B_ / 4, 256, 0, stream>>>(y3p, oW4, ob4, out);
}

// Round 17
// 286.457 us; speedup vs baseline: 1.1294x; 1.0551x over previous
//
#include <hip/hip_runtime.h>

#define B_ 4096
#define F_ 26
#define L_ 10
#define V_ 100000
#define D_ 128

typedef __attribute__((ext_vector_type(8))) short short8;
typedef __attribute__((ext_vector_type(4))) float f32x4;

// fp32 -> packed (hi_bf16 << 16) | lo_bf16, both RNE. value ~= hi + lo.
__device__ inline unsigned pack_split(float f) {
    union { float f; unsigned u; } a; a.f = f;
    unsigned r = (a.u + 0x7FFFu + ((a.u >> 16) & 1u)) >> 16;
    union { unsigned u; float f; } hf; hf.u = r << 16;
    float rem = f - hf.f;
    union { float f; unsigned u; } b; b.f = rem;
    unsigned r2 = (b.u + 0x7FFFu + ((b.u >> 16) & 1u)) >> 16;
    return (r << 16) | (r2 & 0xFFFFu);
}
__device__ inline float unpack_f(unsigned u) {
    union { unsigned u; float f; } h; h.u = u & 0xFFFF0000u;
    union { unsigned u; float f; } l; l.u = u << 16;
    return h.f + l.f;
}

// int32 vs int64 indices: wave-parallel probe of odd words.
__device__ __forceinline__ int detect_stride(const int* __restrict__ iw) {
    const int lane = threadIdx.x & 63;
    return __any(iw[1 + 2 * lane] != 0) ? 1 : 2;
}

// One wave: gather-sum bag (s, f) -> bagp[s][f][128] hi/lo packed.
__device__ __forceinline__ void gather_pair(
    const int* __restrict__ idx_words, const float* __restrict__ tables,
    unsigned* __restrict__ bagp, int s, int f, int st)
{
    const int lane = threadIdx.x & 63;
    const float* tab = tables + (size_t)f * V_ * D_;
    const size_t ibase = (size_t)s * (F_ * L_) + (size_t)f * L_;
    float2 a = {0.f, 0.f};
    #pragma unroll
    for (int l = 0; l < L_; ++l) {
        int v = idx_words[(ibase + l) * st];
        v = v < 0 ? 0 : (v >= V_ ? V_ - 1 : v);
        float2 x = *reinterpret_cast<const float2*>(tab + (size_t)v * D_ + 2 * lane);
        a.x += x.x; a.y += x.y;
    }
    uint2 o;
    o.x = pack_split(a.x);
    o.y = pack_split(a.y);
    *reinterpret_cast<uint2*>(bagp + ((size_t)s * F_ + f) * 128 + 2 * lane) = o;
}

// ---- weight transpose+split tile ----
__device__ void prep_tile(const float* __restrict__ W, unsigned* __restrict__ Wt,
                          int K, int N, int Kp, int local)
{
    __shared__ float tile[32][33];
    const int t = threadIdx.x;
    const int tx = t & 31, ty = t >> 5;
    const int nbt = N >> 5;
    const int nb = (local % nbt) << 5, kb = (local / nbt) << 5;
    #pragma unroll
    for (int i = 0; i < 4; ++i) {
        int k = kb + ty + i * 8;
        tile[ty + i * 8][tx] = (k < K) ? W[(size_t)k * N + nb + tx] : 0.f;
    }
    __syncthreads();
    #pragma unroll
    for (int i = 0; i < 4; ++i) {
        int nl = ty + i * 8;
        Wt[(size_t)(nb + nl) * Kp + kb + tx] = pack_split(tile[tx][nl]);
    }
}

// L1: gather blocks FIRST (bids [0,26624): 4 pairs/block, s-major = r13's
// exact ordering/writes), then 2832 prep blocks fill the gather tail.
// Static LDS = prep's 4.2 KB only -> gather occupancy unaffected (no r14 trap).
__global__ __launch_bounds__(256) void gather_prep(
    const int* idx_words, const float* tables, unsigned* bagp,
    const float* dW0, const float* dW1, const float* dW2,
    const float* oW0, const float* oW1, const float* oW2, const float* oW3,
    unsigned* dWt0, unsigned* dWt1, unsigned* dWt2,
    unsigned* oWt0, unsigned* oWt1, unsigned* oWt2, unsigned* oWt3,
    const float* dense, unsigned* densep)
{
    const int bid = blockIdx.x;
    if (bid < 26624) {
        int g = bid * 4 + (threadIdx.x >> 6);   // s-major, identical to r13
        int s = g / F_;
        int f = g - s * F_;
        int st = detect_stride(idx_words);
        gather_pair(idx_words, tables, bagp, s, f, st);
        return;
    }
    const int pb = bid - 26624;
    if      (pb < 16)   prep_tile(dW0, dWt0, 13,   512,  32,   pb);
    else if (pb < 144)  prep_tile(dW1, dWt1, 512,  256,  512,  pb - 16);
    else if (pb < 176)  prep_tile(dW2, dWt2, 256,  128,  256,  pb - 144);
    else if (pb < 656)  prep_tile(oW0, oWt0, 479,  1024, 480,  pb - 176);
    else if (pb < 1680) prep_tile(oW1, oWt1, 1024, 1024, 1024, pb - 656);
    else if (pb < 2192) prep_tile(oW2, oWt2, 1024, 512,  1024, pb - 1680);
    else if (pb < 2320) prep_tile(oW3, oWt3, 512,  256,  512,  pb - 2192);
    else {
        int g = (pb - 2320) * 256 + threadIdx.x;   // B*32 slots
        int b = g >> 5, k = g & 31;
        densep[g] = (k < 13) ? pack_split(dense[(size_t)b * 13 + k]) : 0u;
    }
}

// TM=128 GEMM: 8 waves (2x4), wave-tile 64x32, dbuf LDS (r8/r13 structure).
__global__ __launch_bounds__(512) void gemm8(
    const unsigned* __restrict__ Ap, const unsigned* __restrict__ Wt,
    const float* __restrict__ bias, unsigned* __restrict__ Cp,
    int N, int Kp)
{
    __shared__ __align__(16) unsigned Au[2][128 * 32];
    __shared__ __align__(16) unsigned Bu[2][128 * 32];

    const int t    = threadIdx.x;
    const int lane = t & 63;
    const int w    = t >> 6;
    const int wm   = w >> 2, wn = w & 3;
    const int m0   = blockIdx.y * 128, n0 = blockIdx.x * 128;

    f32x4 acc[4][2];
    const f32x4 zero = {0.f, 0.f, 0.f, 0.f};
    #pragma unroll
    for (int i = 0; i < 4; ++i)
        #pragma unroll
        for (int j = 0; j < 2; ++j) acc[i][j] = zero;

    const unsigned* Ab = Ap + (size_t)m0 * Kp;
    const unsigned* Bb = Wt + (size_t)n0 * Kp;

    const int g4 = lane >> 4;
    const int rr = lane & 15;

    auto STAGE = [&](int buf, int k0) {
        #pragma unroll
        for (int i = 0; i < 2; ++i) {
            int chunk = t + (i << 9);
            int row = chunk >> 3, ch = chunk & 7;
            int sch = ch ^ (row & 7);
            __builtin_amdgcn_global_load_lds(
                (const __attribute__((address_space(1))) unsigned*)(Ab + (size_t)row * Kp + k0 + (sch << 2)),
                &Au[buf][chunk << 2], 16, 0, 0);
        }
        #pragma unroll
        for (int i = 0; i < 2; ++i) {
            int chunk = t + (i << 9);
            int row = chunk >> 3, ch = chunk & 7;
            int sch = ch ^ (row & 7);
            __builtin_amdgcn_global_load_lds(
                (const __attribute__((address_space(1))) unsigned*)(Bb + (size_t)row * Kp + k0 + (sch << 2)),
                &Bu[buf][chunk << 2], 16, 0, 0);
        }
    };

    auto COMPUTE = [&](int buf) {
        const unsigned* au = Au[buf];
        const unsigned* bu = Bu[buf];
        short8 bh[2], bl[2];
        #pragma unroll
        for (int tj = 0; tj < 2; ++tj) {
            int r = wn * 32 + tj * 16 + rr;
            int c0 = (2 * g4) ^ (r & 7), c1 = (2 * g4 + 1) ^ (r & 7);
            uint4 p = *reinterpret_cast<const uint4*>(&bu[r * 32 + (c0 << 2)]);
            uint4 q = *reinterpret_cast<const uint4*>(&bu[r * 32 + (c1 << 2)]);
            union { short8 s; uint4 u; } H, L;
            H.u.x = __builtin_amdgcn_perm(p.y, p.x, 0x07060302u);
            L.u.x = __builtin_amdgcn_perm(p.y, p.x, 0x05040100u);
            H.u.y = __builtin_amdgcn_perm(p.w, p.z, 0x07060302u);
            L.u.y = __builtin_amdgcn_perm(p.w, p.z, 0x05040100u);
            H.u.z = __builtin_amdgcn_perm(q.y, q.x, 0x07060302u);
            L.u.z = __builtin_amdgcn_perm(q.y, q.x, 0x05040100u);
            H.u.w = __builtin_amdgcn_perm(q.w, q.z, 0x07060302u);
            L.u.w = __builtin_amdgcn_perm(q.w, q.z, 0x05040100u);
            bh[tj] = H.s; bl[tj] = L.s;
        }
        #pragma unroll
        for (int ti = 0; ti < 4; ++ti) {
            int r = wm * 64 + ti * 16 + rr;
            int c0 = (2 * g4) ^ (r & 7), c1 = (2 * g4 + 1) ^ (r & 7);
            uint4 p = *reinterpret_cast<const uint4*>(&au[r * 32 + (c0 << 2)]);
            uint4 q = *reinterpret_cast<const uint4*>(&au[r * 32 + (c1 << 2)]);
            union { short8 s; uint4 u; } H, L;
            H.u.x = __builtin_amdgcn_perm(p.y, p.x, 0x07060302u);
            L.u.x = __builtin_amdgcn_perm(p.y, p.x, 0x05040100u);
            H.u.y = __builtin_amdgcn_perm(p.w, p.z, 0x07060302u);
            L.u.y = __builtin_amdgcn_perm(p.w, p.z, 0x05040100u);
            H.u.z = __builtin_amdgcn_perm(q.y, q.x, 0x07060302u);
            L.u.z = __builtin_amdgcn_perm(q.y, q.x, 0x05040100u);
            H.u.w = __builtin_amdgcn_perm(q.w, q.z, 0x07060302u);
            L.u.w = __builtin_amdgcn_perm(q.w, q.z, 0x05040100u);
            short8 ah = H.s, al = L.s;
            #pragma unroll
            for (int tj = 0; tj < 2; ++tj) {
                f32x4 c = acc[ti][tj];
                c = __builtin_amdgcn_mfma_f32_16x16x32_bf16(ah, bh[tj], c, 0, 0, 0);
                c = __builtin_amdgcn_mfma_f32_16x16x32_bf16(ah, bl[tj], c, 0, 0, 0);
                c = __builtin_amdgcn_mfma_f32_16x16x32_bf16(al, bh[tj], c, 0, 0, 0);
                acc[ti][tj] = c;
            }
        }
    };

    const int nt = Kp >> 5;
    STAGE(0, 0);
    __syncthreads();
    int cur = 0;
    for (int ts = 0; ts < nt - 1; ++ts) {
        STAGE(cur ^ 1, (ts + 1) << 5);
        COMPUTE(cur);
        __syncthreads();
        cur ^= 1;
    }
    COMPUTE(cur);

    #pragma unroll
    for (int ti = 0; ti < 4; ++ti) {
        int row = m0 + wm * 64 + ti * 16 + (g4 << 2);
        #pragma unroll
        for (int tj = 0; tj < 2; ++tj) {
            int col = n0 + wn * 32 + tj * 16 + rr;
            float bv = bias[col];
            #pragma unroll
            for (int r = 0; r < 4; ++r) {
                float v = fmaxf(acc[ti][tj][r] + bv, 0.f);
                Cp[(size_t)(row + r) * N + col] = pack_split(v);
            }
        }
    }
}

// 4 samples per block, one wave per sample (r13, unchanged).
__global__ __launch_bounds__(256) void interact_mfma(
    const unsigned* __restrict__ x2p,
    const unsigned* __restrict__ bagp,
    unsigned*       __restrict__ featsp)
{
    __shared__ unsigned zh[4][32][64];
    __shared__ unsigned zl[4][32][64];

    const int t    = threadIdx.x;
    const int w    = t >> 6;
    const int lane = t & 63;
    const int s    = blockIdx.x * 4 + w;

    uint2 xv = *reinterpret_cast<const uint2*>(x2p + (size_t)s * 128 + 2 * lane);
    *reinterpret_cast<uint2*>(featsp + (size_t)s * 480 + 2 * lane) = xv;
    if (lane == 0) featsp[(size_t)s * 480 + 479] = 0u;
    zh[w][0][lane] = (xv.x >> 16) | (xv.y & 0xFFFF0000u);
    zl[w][0][lane] = (xv.x & 0xFFFFu) | (xv.y << 16);

    for (int f = 0; f < F_; ++f) {
        uint2 u = *reinterpret_cast<const uint2*>(bagp + ((size_t)s * F_ + f) * 128 + 2 * lane);
        int r  = f + 1;
        int dw = (((lane >> 2) ^ (r & 7)) << 2) + (lane & 3);
        zh[w][r][dw] = (u.x >> 16) | (u.y & 0xFFFF0000u);
        zl[w][r][dw] = (u.x & 0xFFFFu) | (u.y << 16);
    }
    __syncthreads();

    const int g4 = lane >> 4;
    const int rr = lane & 15;
    f32x4 acc[2][2];
    const f32x4 zero = {0.f, 0.f, 0.f, 0.f};
    acc[0][0] = zero; acc[0][1] = zero; acc[1][0] = zero; acc[1][1] = zero;

    #pragma unroll
    for (int ks = 0; ks < 4; ++ks) {
        short8 h[2], lo[2];
        #pragma unroll
        for (int mi = 0; mi < 2; ++mi) {
            int r = mi * 16 + rr;
            int c = (ks * 4 + g4) ^ (r & 7);
            h[mi]  = *reinterpret_cast<const short8*>(&zh[w][r][c << 2]);
            lo[mi] = *reinterpret_cast<const short8*>(&zl[w][r][c << 2]);
        }
        #pragma unroll
        for (int mi = 0; mi < 2; ++mi)
            #pragma unroll
            for (int nj = 0; nj < 2; ++nj) {
                f32x4 c = acc[mi][nj];
                c = __builtin_amdgcn_mfma_f32_16x16x32_bf16(h[mi],  h[nj],  c, 0, 0, 0);
                c = __builtin_amdgcn_mfma_f32_16x16x32_bf16(h[mi],  lo[nj], c, 0, 0, 0);
                c = __builtin_amdgcn_mfma_f32_16x16x32_bf16(lo[mi], h[nj],  c, 0, 0, 0);
                acc[mi][nj] = c;
            }
    }

    #pragma unroll
    for (int mi = 0; mi < 2; ++mi) {
        #pragma unroll
        for (int nj = 0; nj < 2; ++nj) {
            #pragma unroll
            for (int r = 0; r < 4; ++r) {
                int i = mi * 16 + g4 * 4 + r;
                int j = nj * 16 + rr;
                if (i < j && j <= 26) {
                    int p = i * 26 - (i * (i - 1)) / 2 + (j - i - 1);
                    featsp[(size_t)s * 480 + 128 + p] = pack_split(acc[mi][nj][r]);
                }
            }
        }
    }
}

// logits[b] = dot(unpack(y3p[b,:256]), w) + bias
__global__ __launch_bounds__(256) void final_dot(
    const unsigned* __restrict__ yp, const float* __restrict__ w,
    const float* __restrict__ bias, float* __restrict__ out)
{
    const int wave = threadIdx.x >> 6;
    const int lane = threadIdx.x & 63;
    const int b = blockIdx.x * 4 + wave;
    uint4 u = *reinterpret_cast<const uint4*>(yp + (size_t)b * 256 + lane * 4);
    float4 wv = *reinterpret_cast<const float4*>(&w[lane * 4]);
    float s = unpack_f(u.x) * wv.x + unpack_f(u.y) * wv.y +
              unpack_f(u.z) * wv.z + unpack_f(u.w) * wv.w;
    #pragma unroll
    for (int off = 32; off; off >>= 1) s += __shfl_xor(s, off);
    if (lane == 0) out[b] = s + bias[0];
}

extern "C" void kernel_launch(void* const* d_in, const int* in_sizes, int n_in,
                              void* d_out, int out_size, void* d_ws, size_t ws_size,
                              hipStream_t stream)
{
    const float* dense   = (const float*)d_in[0];
    const int*   indices = (const int*)  d_in[1];
    const float* tables  = (const float*)d_in[2];
    const float* dW0 = (const float*)d_in[3];  const float* db0 = (const float*)d_in[4];
    const float* dW1 = (const float*)d_in[5];  const float* db1 = (const float*)d_in[6];
    const float* dW2 = (const float*)d_in[7];  const float* db2 = (const float*)d_in[8];
    const float* oW0 = (const float*)d_in[9];  const float* ob0 = (const float*)d_in[10];
    const float* oW1 = (const float*)d_in[11]; const float* ob1 = (const float*)d_in[12];
    const float* oW2 = (const float*)d_in[13]; const float* ob2 = (const float*)d_in[14];
    const float* oW3 = (const float*)d_in[15]; const float* ob3 = (const float*)d_in[16];
    const float* oW4 = (const float*)d_in[17]; const float* ob4 = (const float*)d_in[18];
    float* out = (float*)d_out;

    unsigned* wsu = (unsigned*)d_ws;
    unsigned* dWt0 = wsu + 0;          // [512][32]
    unsigned* dWt1 = wsu + 16384;      // [256][512]
    unsigned* dWt2 = wsu + 147456;     // [128][256]
    unsigned* oWt0 = wsu + 180224;     // [1024][480]
    unsigned* oWt1 = wsu + 671744;     // [1024][1024]
    unsigned* oWt2 = wsu + 1720320;    // [512][1024]
    unsigned* oWt3 = wsu + 2244608;    // [256][512]
    unsigned* densep = wsu + 2375680;  // [4096][32]
    unsigned* x2p    = wsu + 2506752;  // [4096][128]
    unsigned* featsp = wsu + 3031040;  // [4096][480]
    unsigned* x0p    = wsu + 5000000;  // [4096][512]
    unsigned* x1p    = wsu + 7097152;  // [4096][256]
    unsigned* y0p    = wsu + 5000000;  // [4096][1024] (x0p/x1p dead)
    unsigned* y1p    = wsu + 9194304;  // [4096][1024]
    unsigned* y2p    = wsu + 2506752;  // [4096][512]  (x2p/featsp dead)
    unsigned* y3p    = wsu + 5000000;  // [4096][256]  (y0p dead)
    unsigned* bagp   = wsu + 13500000; // [4096][26][128]
    // high water ~108.5 MB

    // L1: gather (26624 blocks, dispatched first) + prep (2832) in one launch
    gather_prep<<<26624 + 2832, 256, 0, stream>>>(
        indices, tables, bagp,
        dW0, dW1, dW2, oW0, oW1, oW2, oW3,
        dWt0, dWt1, dWt2, oWt0, oWt1, oWt2, oWt3,
        dense, densep);

    gemm8<<<dim3(4, 32), 512, 0, stream>>>(densep, dWt0, db0, x0p, 512, 32);
    gemm8<<<dim3(2, 32), 512, 0, stream>>>(x0p,    dWt1, db1, x1p, 256, 512);
    gemm8<<<dim3(1, 32), 512, 0, stream>>>(x1p,    dWt2, db2, x2p, 128, 256);

    interact_mfma<<<B_ / 4, 256, 0, stream>>>(x2p, bagp, featsp);

    gemm8<<<dim3(8, 32), 512, 0, stream>>>(featsp, oWt0, ob0, y0p, 1024, 480);
    gemm8<<<dim3(8, 32), 512, 0, stream>>>(y0p,    oWt1, ob1, y1p, 1024, 1024);
    gemm8<<<dim3(4, 32), 512, 0, stream>>>(y1p,    oWt2, ob2, y2p, 512, 1024);
    gemm8<<<dim3(2, 32), 512, 0, stream>>>(y2p,    oWt3, ob3, y3p, 256, 512);

    final_dot<<<B_ / 4, 256, 0, stream>>>(y3p, oW4, ob4, out);
}